// Round 1
// baseline (3753.801 us; speedup 1.0000x reference)
//
#include <hip/hip_runtime.h>
#include <hip/hip_bf16.h>
#include <math.h>

// Problem constants (verified against in_sizes at launch)
#define HH 128
#define FF 128
#define GG 50
#define NLAYERS 6

static __device__ __forceinline__ float ssp(float x) {
    // jax.nn.softplus(x) - log(2) ; softplus = logaddexp(x, 0)
    return fmaxf(x, 0.f) + log1pf(expf(-fabsf(x))) - 0.6931471805599453f;
}

// ---------------- precompute: dist + cutoff C per edge ----------------
__global__ void precompute_kernel(const float* __restrict__ pos,
                                  const float* __restrict__ offs,
                                  const int* __restrict__ row,
                                  const int* __restrict__ col,
                                  float* __restrict__ dist,
                                  float* __restrict__ Cb, int E_) {
    int e = blockIdx.x * 256 + threadIdx.x;
    if (e >= E_) return;
    int r = row[e], c = col[e];
    float dx = pos[c * 3 + 0] + offs[e * 3 + 0] - pos[r * 3 + 0];
    float dy = pos[c * 3 + 1] + offs[e * 3 + 1] - pos[r * 3 + 1];
    float dz = pos[c * 3 + 2] + offs[e * 3 + 2] - pos[r * 3 + 2];
    float d = sqrtf(dx * dx + dy * dy + dz * dz);
    dist[e] = d;
    Cb[e] = 0.5f * (cosf(d * 0.6283185307179586f) + 1.0f);  // pi/5
}

// ---------------- vproj = v @ lin_w[l]  (N x 128 x 128) ----------------
__global__ __launch_bounds__(128) void vproj_kernel(const float* __restrict__ vb,
                                                    const float* __restrict__ W,
                                                    float* __restrict__ out, int N_) {
    __shared__ float vt[32][HH];
    const int f = threadIdx.x;
    const int n0 = blockIdx.x * 32;
    for (int n = 0; n < 32; n++) {
        int gn = n0 + n;
        vt[n][f] = vb[(size_t)(gn < N_ ? gn : 0) * HH + f];
    }
    __syncthreads();
    for (int nb = 0; nb < 32; nb += 8) {
        float acc[8];
#pragma unroll
        for (int i = 0; i < 8; i++) acc[i] = 0.f;
        for (int k = 0; k < HH; k += 4) {
            float w0 = W[(k + 0) * FF + f], w1v = W[(k + 1) * FF + f];
            float w2v = W[(k + 2) * FF + f], w3 = W[(k + 3) * FF + f];
#pragma unroll
            for (int i = 0; i < 8; i++) {
                float4 hv = *(const float4*)&vt[nb + i][k];
                acc[i] = fmaf(hv.x, w0, acc[i]);
                acc[i] = fmaf(hv.y, w1v, acc[i]);
                acc[i] = fmaf(hv.z, w2v, acc[i]);
                acc[i] = fmaf(hv.w, w3, acc[i]);
            }
        }
#pragma unroll
        for (int i = 0; i < 8; i++) {
            int gn = n0 + nb + i;
            if (gn < N_) out[(size_t)gn * FF + f] = acc[i];
        }
    }
}

// ---------------- fused edge kernel ----------------
// per block: 64 edges, 256 threads (f = tid&127, sub = tid>>7 handles 32 edges)
__global__ __launch_bounds__(256) void edge_kernel(
    const float* __restrict__ dist, const float* __restrict__ Cb,
    const float* __restrict__ vproj, const int* __restrict__ row,
    const int* __restrict__ col, const float* __restrict__ w1,
    const float* __restrict__ b1, const float* __restrict__ w2,
    const float* __restrict__ b2, float* __restrict__ agg, int E_) {
    __shared__ float demb_s[64][56];   // padded rows (16B aligned)
    __shared__ float h1_s[64][FF];
    const float STEP = 5.0f / 49.0f;
    const float COEFF = -0.5f / (STEP * STEP);

    const int f = threadIdx.x & 127;
    const int sub = threadIdx.x >> 7;
    const int e0 = blockIdx.x * 64;

    // demb tile: 64 edges x 50 gaussians
    for (int idx = threadIdx.x; idx < 64 * GG; idx += 256) {
        int e = idx / GG, g = idx - e * GG;
        int ge = e0 + e;
        float d = dist[ge < E_ ? ge : 0];
        float x = fmaf((float)g, -STEP, d);
        demb_s[e][g] = expf(COEFF * x * x);
    }
    __syncthreads();

    // h1 = ssp(demb @ w1 + b1)
    {
        const float bb = b1[f];
        const int ebase = sub * 32;
        for (int eb = 0; eb < 32; eb += 8) {
            float acc[8];
#pragma unroll
            for (int i = 0; i < 8; i++) acc[i] = bb;
#pragma unroll
            for (int g = 0; g < 48; g += 4) {
                float w0 = w1[(g + 0) * FF + f], wv1 = w1[(g + 1) * FF + f];
                float wv2 = w1[(g + 2) * FF + f], w3 = w1[(g + 3) * FF + f];
#pragma unroll
                for (int i = 0; i < 8; i++) {
                    float4 dv = *(const float4*)&demb_s[ebase + eb + i][g];
                    acc[i] = fmaf(dv.x, w0, acc[i]);
                    acc[i] = fmaf(dv.y, wv1, acc[i]);
                    acc[i] = fmaf(dv.z, wv2, acc[i]);
                    acc[i] = fmaf(dv.w, w3, acc[i]);
                }
            }
            {
                float w0 = w1[48 * FF + f], wv1 = w1[49 * FF + f];
#pragma unroll
                for (int i = 0; i < 8; i++) {
                    float2 dv = *(const float2*)&demb_s[ebase + eb + i][48];
                    acc[i] = fmaf(dv.x, w0, acc[i]);
                    acc[i] = fmaf(dv.y, wv1, acc[i]);
                }
            }
#pragma unroll
            for (int i = 0; i < 8; i++) h1_s[ebase + eb + i][f] = ssp(acc[i]);
        }
    }
    __syncthreads();

    // Wf = (h1 @ w2 + b2) * C ; e = vproj[row]*Wf ; atomic agg[col] += e
    {
        const float bb = b2[f];
        const int ebase = sub * 32;
        for (int eb = 0; eb < 32; eb += 8) {
            float acc[8];
#pragma unroll
            for (int i = 0; i < 8; i++) acc[i] = bb;
            for (int k = 0; k < FF; k += 4) {
                float w0 = w2[(k + 0) * FF + f], wv1 = w2[(k + 1) * FF + f];
                float wv2 = w2[(k + 2) * FF + f], w3 = w2[(k + 3) * FF + f];
#pragma unroll
                for (int i = 0; i < 8; i++) {
                    float4 hv = *(const float4*)&h1_s[ebase + eb + i][k];
                    acc[i] = fmaf(hv.x, w0, acc[i]);
                    acc[i] = fmaf(hv.y, wv1, acc[i]);
                    acc[i] = fmaf(hv.z, wv2, acc[i]);
                    acc[i] = fmaf(hv.w, w3, acc[i]);
                }
            }
#pragma unroll
            for (int i = 0; i < 8; i++) {
                int ge = e0 + ebase + eb + i;
                if (ge < E_) {
                    float wf = acc[i] * Cb[ge];
                    float val = vproj[(size_t)row[ge] * FF + f] * wf;
                    unsafeAtomicAdd(&agg[(size_t)col[ge] * FF + f], val);
                }
            }
        }
    }
}

// ---------------- node update: v += ssp(agg@u1+ub1)@u2+ub2 ----------------
__global__ __launch_bounds__(128) void node_kernel(
    const float* __restrict__ agg, const float* __restrict__ u1,
    const float* __restrict__ ub1, const float* __restrict__ u2,
    const float* __restrict__ ub2, float* __restrict__ vb, int N_) {
    __shared__ float at[32][FF];
    __shared__ float t1[32][HH];
    const int f = threadIdx.x;
    const int n0 = blockIdx.x * 32;
    for (int n = 0; n < 32; n++) {
        int gn = n0 + n;
        at[n][f] = agg[(size_t)(gn < N_ ? gn : 0) * FF + f];
    }
    __syncthreads();
    {
        const float bb = ub1[f];
        for (int nb = 0; nb < 32; nb += 8) {
            float acc[8];
#pragma unroll
            for (int i = 0; i < 8; i++) acc[i] = bb;
            for (int k = 0; k < FF; k += 4) {
                float w0 = u1[(k + 0) * HH + f], wv1 = u1[(k + 1) * HH + f];
                float wv2 = u1[(k + 2) * HH + f], w3 = u1[(k + 3) * HH + f];
#pragma unroll
                for (int i = 0; i < 8; i++) {
                    float4 hv = *(const float4*)&at[nb + i][k];
                    acc[i] = fmaf(hv.x, w0, acc[i]);
                    acc[i] = fmaf(hv.y, wv1, acc[i]);
                    acc[i] = fmaf(hv.z, wv2, acc[i]);
                    acc[i] = fmaf(hv.w, w3, acc[i]);
                }
            }
#pragma unroll
            for (int i = 0; i < 8; i++) t1[nb + i][f] = ssp(acc[i]);
        }
    }
    __syncthreads();
    {
        const float bb = ub2[f];
        for (int nb = 0; nb < 32; nb += 8) {
            float acc[8];
#pragma unroll
            for (int i = 0; i < 8; i++) acc[i] = bb;
            for (int k = 0; k < HH; k += 4) {
                float w0 = u2[(k + 0) * HH + f], wv1 = u2[(k + 1) * HH + f];
                float wv2 = u2[(k + 2) * HH + f], w3 = u2[(k + 3) * HH + f];
#pragma unroll
                for (int i = 0; i < 8; i++) {
                    float4 hv = *(const float4*)&t1[nb + i][k];
                    acc[i] = fmaf(hv.x, w0, acc[i]);
                    acc[i] = fmaf(hv.y, wv1, acc[i]);
                    acc[i] = fmaf(hv.z, wv2, acc[i]);
                    acc[i] = fmaf(hv.w, w3, acc[i]);
                }
            }
#pragma unroll
            for (int i = 0; i < 8; i++) {
                int gn = n0 + nb + i;
                if (gn < N_) vb[(size_t)gn * HH + f] += acc[i];
            }
        }
    }
}

extern "C" void kernel_launch(void* const* d_in, const int* in_sizes, int n_in,
                              void* d_out, int out_size, void* d_ws, size_t ws_size,
                              hipStream_t stream) {
    const float* v = (const float*)d_in[0];
    const float* pos = (const float*)d_in[1];
    const float* offs = (const float*)d_in[2];
    const int* edges = (const int*)d_in[3];
    const float* lin_w = (const float*)d_in[4];
    const float* w1 = (const float*)d_in[5];
    const float* b1 = (const float*)d_in[6];
    const float* w2 = (const float*)d_in[7];
    const float* b2 = (const float*)d_in[8];
    const float* u1 = (const float*)d_in[9];
    const float* ub1 = (const float*)d_in[10];
    const float* u2 = (const float*)d_in[11];
    const float* ub2 = (const float*)d_in[12];

    const int N = in_sizes[0] / HH;
    const int E = in_sizes[3] / 2;
    const int* row = edges;
    const int* col = edges + E;

    float* ws = (float*)d_ws;
    float* dist = ws;                          // E
    float* Cb = dist + E;                      // E
    float* vproj = Cb + E;                     // N*F
    float* agg = vproj + (size_t)N * FF;       // N*F
    float* vbuf = agg + (size_t)N * FF;        // N*H

    hipMemcpyAsync(vbuf, v, (size_t)N * HH * sizeof(float),
                   hipMemcpyDeviceToDevice, stream);
    precompute_kernel<<<(E + 255) / 256, 256, 0, stream>>>(pos, offs, row, col,
                                                           dist, Cb, E);
    for (int l = 0; l < NLAYERS; l++) {
        vproj_kernel<<<(N + 31) / 32, 128, 0, stream>>>(
            vbuf, lin_w + (size_t)l * HH * FF, vproj, N);
        hipMemsetAsync(agg, 0, (size_t)N * FF * sizeof(float), stream);
        edge_kernel<<<(E + 63) / 64, 256, 0, stream>>>(
            dist, Cb, vproj, row, col, w1 + (size_t)l * GG * FF,
            b1 + (size_t)l * FF, w2 + (size_t)l * FF * FF, b2 + (size_t)l * FF,
            agg, E);
        node_kernel<<<(N + 31) / 32, 128, 0, stream>>>(
            agg, u1 + (size_t)l * FF * HH, ub1 + (size_t)l * HH,
            u2 + (size_t)l * HH * HH, ub2 + (size_t)l * HH, vbuf, N);
    }
    hipMemcpyAsync(d_out, vbuf, (size_t)N * HH * sizeof(float),
                   hipMemcpyDeviceToDevice, stream);
}

// Round 2
// 1705.225 us; speedup vs baseline: 2.2014x; 2.2014x over previous
//
#include <hip/hip_runtime.h>
#include <hip/hip_bf16.h>
#include <math.h>

#define HH 128
#define FF 128
#define GG 50
#define NLAYERS 6

typedef __attribute__((ext_vector_type(8))) short bf16x8;
typedef __attribute__((ext_vector_type(4))) float f32x4;

static __device__ __forceinline__ float ssp(float x) {
    // softplus(x) - log(2), fast path via v_exp/v_log
    return fmaxf(x, 0.f) + __logf(1.f + __expf(-fabsf(x))) - 0.6931471805599453f;
}

static __device__ __forceinline__ short f2bf(float x) {
    union { float f; unsigned u; } c; c.f = x;
    unsigned r = (c.u + 0x7FFF + ((c.u >> 16) & 1)) >> 16;
    return (short)r;
}

// ---------------- precompute: dist + cutoff C per edge ----------------
__global__ void precompute_kernel(const float* __restrict__ pos,
                                  const float* __restrict__ offs,
                                  const int* __restrict__ row,
                                  const int* __restrict__ col,
                                  float* __restrict__ dist,
                                  float* __restrict__ Cb, int E_) {
    int e = blockIdx.x * 256 + threadIdx.x;
    if (e >= E_) return;
    int r = row[e], c = col[e];
    float dx = pos[c * 3 + 0] + offs[e * 3 + 0] - pos[r * 3 + 0];
    float dy = pos[c * 3 + 1] + offs[e * 3 + 1] - pos[r * 3 + 1];
    float dz = pos[c * 3 + 2] + offs[e * 3 + 2] - pos[r * 3 + 2];
    float d = sqrtf(dx * dx + dy * dy + dz * dz);
    dist[e] = d;
    Cb[e] = 0.5f * (cosf(d * 0.6283185307179586f) + 1.0f);  // pi/5
}

// ---------------- prep: transpose+bf16 filter weights for all layers -------
__global__ __launch_bounds__(256) void prep_kernel(const float* __restrict__ w1,
                                                   const float* __restrict__ w2,
                                                   short* __restrict__ w1t,
                                                   short* __restrict__ w2t) {
    int idx = blockIdx.x * 256 + threadIdx.x;
    if (idx < NLAYERS * FF * FF) {  // w2t[l][fout][fin] = w2[l][fin][fout]
        int l = idx >> 14, r = idx & 16383, fo = r >> 7, fi = r & 127;
        w2t[idx] = f2bf(w2[(size_t)l * FF * FF + fi * FF + fo]);
    }
    if (idx < NLAYERS * FF * 64) {  // w1t[l][fout][g pad 64] = w1[l][g][fout]
        int l = idx >> 13, r = idx & 8191, fo = r >> 6, g = r & 63;
        w1t[idx] = f2bf(g < GG ? w1[((size_t)l * GG + g) * FF + fo] : 0.f);
    }
}

// ---------------- vproj = v @ lin_w[l]  (N x 128 x 128) ----------------
__global__ __launch_bounds__(128) void vproj_kernel(const float* __restrict__ vb,
                                                    const float* __restrict__ W,
                                                    float* __restrict__ out, int N_) {
    __shared__ float vt[32][HH];
    const int f = threadIdx.x;
    const int n0 = blockIdx.x * 32;
    for (int n = 0; n < 32; n++) {
        int gn = n0 + n;
        vt[n][f] = vb[(size_t)(gn < N_ ? gn : 0) * HH + f];
    }
    __syncthreads();
    for (int nb = 0; nb < 32; nb += 8) {
        float acc[8];
#pragma unroll
        for (int i = 0; i < 8; i++) acc[i] = 0.f;
        for (int k = 0; k < HH; k += 4) {
            float w0 = W[(k + 0) * FF + f], w1v = W[(k + 1) * FF + f];
            float w2v = W[(k + 2) * FF + f], w3 = W[(k + 3) * FF + f];
#pragma unroll
            for (int i = 0; i < 8; i++) {
                float4 hv = *(const float4*)&vt[nb + i][k];
                acc[i] = fmaf(hv.x, w0, acc[i]);
                acc[i] = fmaf(hv.y, w1v, acc[i]);
                acc[i] = fmaf(hv.z, w2v, acc[i]);
                acc[i] = fmaf(hv.w, w3, acc[i]);
            }
        }
#pragma unroll
        for (int i = 0; i < 8; i++) {
            int gn = n0 + nb + i;
            if (gn < N_) out[(size_t)gn * FF + f] = acc[i];
        }
    }
}

// ---------------- fused edge kernel (bf16 MFMA) ----------------
// 64 edges/block, 4 waves; wave w owns f-range [w*32, w*32+32)
__global__ __launch_bounds__(256) void edge_mfma_kernel(
    const float* __restrict__ dist, const float* __restrict__ Cb,
    const float* __restrict__ vproj, const int* __restrict__ row,
    const int* __restrict__ col, const short* __restrict__ w1t,
    const float* __restrict__ b1, const short* __restrict__ w2t,
    const float* __restrict__ b2, float* __restrict__ agg, int E_) {
    __shared__ short demb_s[64][72];   // 144B row stride -> 2-way (free)
    __shared__ short h1_s[64][136];    // 272B row stride -> 2-way (free)
    const int tid = threadIdx.x;
    const int lane = tid & 63;
    const int wave = tid >> 6;
    const int l15 = lane & 15;
    const int l4 = lane >> 4;  // 0..3
    const int n0 = wave * 32;
    const int e0 = blockIdx.x * 64;

    // B fragments (registers, reused across all 64 edges)
    bf16x8 bw1[2][2];  // [ntile][kstep]  GEMM1: K=64 (padded 50)
    bf16x8 bw2[2][4];  // [ntile][kstep]  GEMM2: K=128
    float bias1[2], bias2[2];
#pragma unroll
    for (int n = 0; n < 2; n++) {
        const int fo = n0 + n * 16 + l15;
        bias1[n] = b1[fo];
        bias2[n] = b2[fo];
#pragma unroll
        for (int ks = 0; ks < 2; ks++)
            bw1[n][ks] = *(const bf16x8*)&w1t[fo * 64 + ks * 32 + l4 * 8];
#pragma unroll
        for (int ks = 0; ks < 4; ks++)
            bw2[n][ks] = *(const bf16x8*)&w2t[fo * 128 + ks * 32 + l4 * 8];
    }

    // demb tile: 64 edges x 64 (g>=50 zero-padded)
    const float STEP = 5.0f / 49.0f;
    const float COEFF = -0.5f / (STEP * STEP);
    for (int idx = tid; idx < 64 * 64; idx += 256) {
        int e = idx >> 6, g = idx & 63;
        int ge = e0 + e;
        float d = dist[ge < E_ ? ge : 0];
        float x = fmaf((float)g, -STEP, d);
        float val = (g < GG) ? __expf(COEFF * x * x) : 0.f;
        demb_s[e][g] = f2bf(val);
    }
    __syncthreads();

    // GEMM1: h1 = ssp(demb @ w1 + b1)  -> h1_s (bf16)
#pragma unroll
    for (int m = 0; m < 4; m++) {
        bf16x8 a0 = *(const bf16x8*)&demb_s[m * 16 + l15][l4 * 8];
        bf16x8 a1 = *(const bf16x8*)&demb_s[m * 16 + l15][32 + l4 * 8];
#pragma unroll
        for (int n = 0; n < 2; n++) {
            f32x4 acc = {bias1[n], bias1[n], bias1[n], bias1[n]};
            acc = __builtin_amdgcn_mfma_f32_16x16x32_bf16(a0, bw1[n][0], acc, 0, 0, 0);
            acc = __builtin_amdgcn_mfma_f32_16x16x32_bf16(a1, bw1[n][1], acc, 0, 0, 0);
            const int f = n0 + n * 16 + l15;
#pragma unroll
            for (int r = 0; r < 4; r++) {
                int er = m * 16 + l4 * 4 + r;
                h1_s[er][f] = f2bf(ssp(acc[r]));
            }
        }
    }
    __syncthreads();

    // GEMM2: Wf = (h1 @ w2 + b2) * C ; e = vproj[row]*Wf ; atomic agg[col] += e
#pragma unroll
    for (int m = 0; m < 4; m++) {
        f32x4 acc0 = {bias2[0], bias2[0], bias2[0], bias2[0]};
        f32x4 acc1 = {bias2[1], bias2[1], bias2[1], bias2[1]};
#pragma unroll
        for (int ks = 0; ks < 4; ks++) {
            bf16x8 a = *(const bf16x8*)&h1_s[m * 16 + l15][ks * 32 + l4 * 8];
            acc0 = __builtin_amdgcn_mfma_f32_16x16x32_bf16(a, bw2[0][ks], acc0, 0, 0, 0);
            acc1 = __builtin_amdgcn_mfma_f32_16x16x32_bf16(a, bw2[1][ks], acc1, 0, 0, 0);
        }
#pragma unroll
        for (int r = 0; r < 4; r++) {
            const int ge = e0 + m * 16 + l4 * 4 + r;
            if (ge < E_) {
                const float cb = Cb[ge];
                const int ri = row[ge], ci = col[ge];
                {
                    const int f = n0 + l15;
                    float val = acc0[r] * cb * vproj[(size_t)ri * FF + f];
                    unsafeAtomicAdd(&agg[(size_t)ci * FF + f], val);
                }
                {
                    const int f = n0 + 16 + l15;
                    float val = acc1[r] * cb * vproj[(size_t)ri * FF + f];
                    unsafeAtomicAdd(&agg[(size_t)ci * FF + f], val);
                }
            }
        }
    }
}

// ---------------- node update: v += ssp(agg@u1+ub1)@u2+ub2 ----------------
__global__ __launch_bounds__(128) void node_kernel(
    const float* __restrict__ agg, const float* __restrict__ u1,
    const float* __restrict__ ub1, const float* __restrict__ u2,
    const float* __restrict__ ub2, float* __restrict__ vb, int N_) {
    __shared__ float at[32][FF];
    __shared__ float t1[32][HH];
    const int f = threadIdx.x;
    const int n0 = blockIdx.x * 32;
    for (int n = 0; n < 32; n++) {
        int gn = n0 + n;
        at[n][f] = agg[(size_t)(gn < N_ ? gn : 0) * FF + f];
    }
    __syncthreads();
    {
        const float bb = ub1[f];
        for (int nb = 0; nb < 32; nb += 8) {
            float acc[8];
#pragma unroll
            for (int i = 0; i < 8; i++) acc[i] = bb;
            for (int k = 0; k < FF; k += 4) {
                float w0 = u1[(k + 0) * HH + f], wv1 = u1[(k + 1) * HH + f];
                float wv2 = u1[(k + 2) * HH + f], w3 = u1[(k + 3) * HH + f];
#pragma unroll
                for (int i = 0; i < 8; i++) {
                    float4 hv = *(const float4*)&at[nb + i][k];
                    acc[i] = fmaf(hv.x, w0, acc[i]);
                    acc[i] = fmaf(hv.y, wv1, acc[i]);
                    acc[i] = fmaf(hv.z, wv2, acc[i]);
                    acc[i] = fmaf(hv.w, w3, acc[i]);
                }
            }
#pragma unroll
            for (int i = 0; i < 8; i++) t1[nb + i][f] = ssp(acc[i]);
        }
    }
    __syncthreads();
    {
        const float bb = ub2[f];
        for (int nb = 0; nb < 32; nb += 8) {
            float acc[8];
#pragma unroll
            for (int i = 0; i < 8; i++) acc[i] = bb;
            for (int k = 0; k < HH; k += 4) {
                float w0 = u2[(k + 0) * HH + f], wv1 = u2[(k + 1) * HH + f];
                float wv2 = u2[(k + 2) * HH + f], w3 = u2[(k + 3) * HH + f];
#pragma unroll
                for (int i = 0; i < 8; i++) {
                    float4 hv = *(const float4*)&t1[nb + i][k];
                    acc[i] = fmaf(hv.x, w0, acc[i]);
                    acc[i] = fmaf(hv.y, wv1, acc[i]);
                    acc[i] = fmaf(hv.z, wv2, acc[i]);
                    acc[i] = fmaf(hv.w, w3, acc[i]);
                }
            }
#pragma unroll
            for (int i = 0; i < 8; i++) {
                int gn = n0 + nb + i;
                if (gn < N_) vb[(size_t)gn * HH + f] += acc[i];
            }
        }
    }
}

extern "C" void kernel_launch(void* const* d_in, const int* in_sizes, int n_in,
                              void* d_out, int out_size, void* d_ws, size_t ws_size,
                              hipStream_t stream) {
    const float* v = (const float*)d_in[0];
    const float* pos = (const float*)d_in[1];
    const float* offs = (const float*)d_in[2];
    const int* edges = (const int*)d_in[3];
    const float* lin_w = (const float*)d_in[4];
    const float* w1 = (const float*)d_in[5];
    const float* b1 = (const float*)d_in[6];
    const float* w2 = (const float*)d_in[7];
    const float* b2 = (const float*)d_in[8];
    const float* u1 = (const float*)d_in[9];
    const float* ub1 = (const float*)d_in[10];
    const float* u2 = (const float*)d_in[11];
    const float* ub2 = (const float*)d_in[12];

    const int N = in_sizes[0] / HH;
    const int E = in_sizes[3] / 2;
    const int* row = edges;
    const int* col = edges + E;

    float* ws = (float*)d_ws;
    float* dist = ws;                         // E
    float* Cb = dist + E;                     // E
    float* vproj = Cb + E;                    // N*F
    float* agg = vproj + (size_t)N * FF;      // N*F
    float* vbuf = agg + (size_t)N * FF;       // N*H
    short* w1t = (short*)(vbuf + (size_t)N * HH);      // 6*128*64 bf16
    short* w2t = w1t + (size_t)NLAYERS * FF * 64;      // 6*128*128 bf16

    hipMemcpyAsync(vbuf, v, (size_t)N * HH * sizeof(float),
                   hipMemcpyDeviceToDevice, stream);
    precompute_kernel<<<(E + 255) / 256, 256, 0, stream>>>(pos, offs, row, col,
                                                           dist, Cb, E);
    prep_kernel<<<(NLAYERS * FF * FF + 255) / 256, 256, 0, stream>>>(w1, w2, w1t, w2t);

    for (int l = 0; l < NLAYERS; l++) {
        vproj_kernel<<<(N + 31) / 32, 128, 0, stream>>>(
            vbuf, lin_w + (size_t)l * HH * FF, vproj, N);
        hipMemsetAsync(agg, 0, (size_t)N * FF * sizeof(float), stream);
        edge_mfma_kernel<<<(E + 63) / 64, 256, 0, stream>>>(
            dist, Cb, vproj, row, col, w1t + (size_t)l * FF * 64,
            b1 + (size_t)l * FF, w2t + (size_t)l * FF * FF, b2 + (size_t)l * FF,
            agg, E);
        node_kernel<<<(N + 31) / 32, 128, 0, stream>>>(
            agg, u1 + (size_t)l * FF * HH, ub1 + (size_t)l * HH,
            u2 + (size_t)l * HH * HH, ub2 + (size_t)l * HH, vbuf, N);
    }
    hipMemcpyAsync(d_out, vbuf, (size_t)N * HH * sizeof(float),
                   hipMemcpyDeviceToDevice, stream);
}

// Round 3
// 1287.857 us; speedup vs baseline: 2.9148x; 1.3241x over previous
//
#include <hip/hip_runtime.h>
#include <hip/hip_bf16.h>
#include <math.h>

#define HH 128
#define FF 128
#define GG 50
#define NLAYERS 6

typedef __attribute__((ext_vector_type(8))) short bf16x8;
typedef __attribute__((ext_vector_type(4))) float f32x4;

static __device__ __forceinline__ float ssp(float x) {
    return fmaxf(x, 0.f) + __logf(1.f + __expf(-fabsf(x))) - 0.6931471805599453f;
}

static __device__ __forceinline__ short f2bf(float x) {
    union { float f; unsigned u; } c; c.f = x;
    unsigned r = (c.u + 0x7FFF + ((c.u >> 16) & 1)) >> 16;
    return (short)r;
}

// ---------------- sort pipeline: hist -> scan -> scatter ----------------
__global__ void hist_kernel(const int* __restrict__ col, int* __restrict__ counts, int E_) {
    int e = blockIdx.x * 256 + threadIdx.x;
    if (e < E_) atomicAdd(&counts[col[e]], 1);
}

__global__ __launch_bounds__(1024) void scan_kernel(const int* __restrict__ counts,
                                                    int* __restrict__ offsets, int N_) {
    __shared__ int buf[1024];
    __shared__ int carry;
    if (threadIdx.x == 0) carry = 0;
    __syncthreads();
    for (int base = 0; base < N_; base += 1024) {
        int i = base + threadIdx.x;
        int val = (i < N_) ? counts[i] : 0;
        buf[threadIdx.x] = val;
        __syncthreads();
        for (int d = 1; d < 1024; d <<= 1) {
            int t = (threadIdx.x >= d) ? buf[threadIdx.x - d] : 0;
            __syncthreads();
            buf[threadIdx.x] += t;
            __syncthreads();
        }
        if (i < N_) offsets[i] = carry + buf[threadIdx.x] - val;  // exclusive
        __syncthreads();
        if (threadIdx.x == 1023) carry += buf[1023];
        __syncthreads();
    }
}

// scatter + compute dist/cutoff per edge into sorted slots
__global__ void scatter_kernel(const float* __restrict__ pos,
                               const float* __restrict__ offs,
                               const int* __restrict__ row,
                               const int* __restrict__ col,
                               int* __restrict__ woff,
                               int* __restrict__ srow, int* __restrict__ scol,
                               float* __restrict__ sdist, float* __restrict__ sCb,
                               int E_) {
    int e = blockIdx.x * 256 + threadIdx.x;
    if (e >= E_) return;
    int r = row[e], c = col[e];
    float dx = pos[c * 3 + 0] + offs[e * 3 + 0] - pos[r * 3 + 0];
    float dy = pos[c * 3 + 1] + offs[e * 3 + 1] - pos[r * 3 + 1];
    float dz = pos[c * 3 + 2] + offs[e * 3 + 2] - pos[r * 3 + 2];
    float d = sqrtf(dx * dx + dy * dy + dz * dz);
    int p = atomicAdd(&woff[c], 1);
    srow[p] = r;
    scol[p] = c;
    sdist[p] = d;
    sCb[p] = 0.5f * (cosf(d * 0.6283185307179586f) + 1.0f);
}

// ------------- prep: transpose + bf16 all weights (all layers) -------------
__global__ __launch_bounds__(256) void prep_kernel(
    const float* __restrict__ w1, const float* __restrict__ w2,
    const float* __restrict__ u1, const float* __restrict__ u2,
    const float* __restrict__ lin_w,
    short* __restrict__ w1t, short* __restrict__ w2t,
    short* __restrict__ u1t, short* __restrict__ u2t, short* __restrict__ lin_wt) {
    int idx = blockIdx.x * 256 + threadIdx.x;
    if (idx < NLAYERS * FF * FF) {
        int l = idx >> 14, r = idx & 16383, a = r >> 7, b = r & 127;
        size_t src = (size_t)l * FF * FF + (size_t)b * FF + a;  // [l][b][a]
        w2t[idx] = f2bf(w2[src]);
        u1t[idx] = f2bf(u1[src]);
        u2t[idx] = f2bf(u2[src]);
        lin_wt[idx] = f2bf(lin_w[src]);
    }
    if (idx < NLAYERS * FF * 64) {
        int l = idx >> 13, r = idx & 8191, fo = r >> 6, g = r & 63;
        w1t[idx] = f2bf(g < GG ? w1[((size_t)l * GG + g) * FF + fo] : 0.f);
    }
}

// ---------------- vproj0 = v(f32) @ lin_w[0]  via MFMA ----------------
__global__ __launch_bounds__(256) void vproj0_kernel(const float* __restrict__ vb,
                                                     const short* __restrict__ lwt,
                                                     float* __restrict__ out, int N_) {
    const int tid = threadIdx.x;
    const int lane = tid & 63, wave = tid >> 6;
    const int l15 = lane & 15, l4 = lane >> 4;
    const int n0 = wave * 32;
    const int nb0 = blockIdx.x * 64;
    bf16x8 bw[2][4];
#pragma unroll
    for (int n = 0; n < 2; n++)
#pragma unroll
        for (int ks = 0; ks < 4; ks++)
            bw[n][ks] = *(const bf16x8*)&lwt[(n0 + n * 16 + l15) * 128 + ks * 32 + l4 * 8];
#pragma unroll
    for (int m = 0; m < 4; m++) {
        f32x4 acc0 = {0.f, 0.f, 0.f, 0.f}, acc1 = {0.f, 0.f, 0.f, 0.f};
        int arow = nb0 + m * 16 + l15;
        const float* ap = &vb[(size_t)(arow < N_ ? arow : 0) * HH];
#pragma unroll
        for (int ks = 0; ks < 4; ks++) {
            float4 x0 = *(const float4*)&ap[ks * 32 + l4 * 8];
            float4 x1 = *(const float4*)&ap[ks * 32 + l4 * 8 + 4];
            bf16x8 a = {f2bf(x0.x), f2bf(x0.y), f2bf(x0.z), f2bf(x0.w),
                        f2bf(x1.x), f2bf(x1.y), f2bf(x1.z), f2bf(x1.w)};
            acc0 = __builtin_amdgcn_mfma_f32_16x16x32_bf16(a, bw[0][ks], acc0, 0, 0, 0);
            acc1 = __builtin_amdgcn_mfma_f32_16x16x32_bf16(a, bw[1][ks], acc1, 0, 0, 0);
        }
#pragma unroll
        for (int r = 0; r < 4; r++) {
            int gn = nb0 + m * 16 + l4 * 4 + r;
            if (gn < N_) {
                out[(size_t)gn * FF + n0 + l15] = acc0[r];
                out[(size_t)gn * FF + n0 + 16 + l15] = acc1[r];
            }
        }
    }
}

// ---------------- fused edge kernel (MFMA + sorted-run scatter) ----------------
__global__ __launch_bounds__(256) void edge_mfma_kernel(
    const float* __restrict__ sdist, const float* __restrict__ sCb,
    const float* __restrict__ vproj, const int* __restrict__ srow,
    const int* __restrict__ scol, const short* __restrict__ w1t,
    const float* __restrict__ b1, const short* __restrict__ w2t,
    const float* __restrict__ b2, float* __restrict__ agg, int E_) {
    __shared__ __align__(16) float wf_s[64][132];      // 33792 B, aliased below
    short* demb_s = (short*)&wf_s[0][0];               // [64][72]
    short* h1_s = demb_s + 64 * 72;                    // [64][136]
    const int tid = threadIdx.x;
    const int lane = tid & 63, wave = tid >> 6;
    const int l15 = lane & 15, l4 = lane >> 4;
    const int n0 = wave * 32;
    const int e0 = blockIdx.x * 64;

    bf16x8 bw1[2][2], bw2[2][4];
    float bias1[2], bias2[2];
#pragma unroll
    for (int n = 0; n < 2; n++) {
        const int fo = n0 + n * 16 + l15;
        bias1[n] = b1[fo];
        bias2[n] = b2[fo];
#pragma unroll
        for (int ks = 0; ks < 2; ks++)
            bw1[n][ks] = *(const bf16x8*)&w1t[fo * 64 + ks * 32 + l4 * 8];
#pragma unroll
        for (int ks = 0; ks < 4; ks++)
            bw2[n][ks] = *(const bf16x8*)&w2t[fo * 128 + ks * 32 + l4 * 8];
    }

    const float STEP = 5.0f / 49.0f;
    const float COEFF = -0.5f / (STEP * STEP);
    for (int idx = tid; idx < 64 * 64; idx += 256) {
        int e = idx >> 6, g = idx & 63;
        int ge = e0 + e;
        float d = sdist[ge < E_ ? ge : 0];
        float x = fmaf((float)g, -STEP, d);
        demb_s[e * 72 + g] = f2bf((g < GG) ? __expf(COEFF * x * x) : 0.f);
    }
    __syncthreads();

    // GEMM1: h1 = ssp(demb @ w1 + b1)
#pragma unroll
    for (int m = 0; m < 4; m++) {
        bf16x8 a0 = *(const bf16x8*)&demb_s[(m * 16 + l15) * 72 + l4 * 8];
        bf16x8 a1 = *(const bf16x8*)&demb_s[(m * 16 + l15) * 72 + 32 + l4 * 8];
#pragma unroll
        for (int n = 0; n < 2; n++) {
            f32x4 acc = {bias1[n], bias1[n], bias1[n], bias1[n]};
            acc = __builtin_amdgcn_mfma_f32_16x16x32_bf16(a0, bw1[n][0], acc, 0, 0, 0);
            acc = __builtin_amdgcn_mfma_f32_16x16x32_bf16(a1, bw1[n][1], acc, 0, 0, 0);
            const int f = n0 + n * 16 + l15;
#pragma unroll
            for (int r = 0; r < 4; r++)
                h1_s[(m * 16 + l4 * 4 + r) * 136 + f] = f2bf(ssp(acc[r]));
        }
    }
    __syncthreads();

    // GEMM2 into registers
    f32x4 accA[4], accB[4];
#pragma unroll
    for (int m = 0; m < 4; m++) {
        accA[m] = {bias2[0], bias2[0], bias2[0], bias2[0]};
        accB[m] = {bias2[1], bias2[1], bias2[1], bias2[1]};
#pragma unroll
        for (int ks = 0; ks < 4; ks++) {
            bf16x8 a = *(const bf16x8*)&h1_s[(m * 16 + l15) * 136 + ks * 32 + l4 * 8];
            accA[m] = __builtin_amdgcn_mfma_f32_16x16x32_bf16(a, bw2[0][ks], accA[m], 0, 0, 0);
            accB[m] = __builtin_amdgcn_mfma_f32_16x16x32_bf16(a, bw2[1][ks], accB[m], 0, 0, 0);
        }
    }
    __syncthreads();  // done with h1_s; wf_s may now overwrite

    // store Wf * C to LDS
#pragma unroll
    for (int m = 0; m < 4; m++) {
#pragma unroll
        for (int r = 0; r < 4; r++) {
            int er = m * 16 + l4 * 4 + r;
            int ge = e0 + er;
            float cb = (ge < E_) ? sCb[ge] : 0.f;
            wf_s[er][n0 + l15] = accA[m][r] * cb;
            wf_s[er][n0 + 16 + l15] = accB[m][r] * cb;
        }
    }
    __syncthreads();

    // serial walk over sorted edges: run-accumulate, flush on col change
    {
        const int f = tid & 127;
        const int sub = tid >> 7;
        const int base = sub * 32;
        if (e0 + base < E_) {
            float acc = 0.f;
            int cur = scol[e0 + base];
#pragma unroll 8
            for (int i = 0; i < 32; i++) {
                int ge = e0 + base + i;
                if (ge >= E_) break;
                int r_ = srow[ge];
                int c_ = scol[ge];
                float val = wf_s[base + i][f] * vproj[(size_t)r_ * FF + f];
                if (c_ != cur) {
                    unsafeAtomicAdd(&agg[(size_t)cur * FF + f], acc);
                    acc = 0.f;
                    cur = c_;
                }
                acc += val;
            }
            unsafeAtomicAdd(&agg[(size_t)cur * FF + f], acc);
        }
    }
}

// ------- fused node kernel: v += ssp(agg@u1+b)@u2+b ; vproj_next -------
__global__ __launch_bounds__(256) void node_mfma_kernel(
    const float* __restrict__ agg, const short* __restrict__ u1t,
    const float* __restrict__ ub1, const short* __restrict__ u2t,
    const float* __restrict__ ub2, float* __restrict__ vb,
    const short* __restrict__ lwt_next, float* __restrict__ vproj, int N_) {
    __shared__ __align__(16) short t1_s[64 * 136];
    __shared__ __align__(16) short t2_s[64 * 136];
    const int tid = threadIdx.x;
    const int lane = tid & 63, wave = tid >> 6;
    const int l15 = lane & 15, l4 = lane >> 4;
    const int n0 = wave * 32;
    const int nb0 = blockIdx.x * 64;

    // GEMM1: t1 = ssp(agg @ u1 + ub1)
    {
        bf16x8 bw[2][4];
        float bias[2];
#pragma unroll
        for (int n = 0; n < 2; n++) {
            bias[n] = ub1[n0 + n * 16 + l15];
#pragma unroll
            for (int ks = 0; ks < 4; ks++)
                bw[n][ks] = *(const bf16x8*)&u1t[(n0 + n * 16 + l15) * 128 + ks * 32 + l4 * 8];
        }
#pragma unroll
        for (int m = 0; m < 4; m++) {
            int arow = nb0 + m * 16 + l15;
            const float* ap = &agg[(size_t)(arow < N_ ? arow : 0) * FF];
            f32x4 acc0 = {bias[0], bias[0], bias[0], bias[0]};
            f32x4 acc1 = {bias[1], bias[1], bias[1], bias[1]};
#pragma unroll
            for (int ks = 0; ks < 4; ks++) {
                float4 x0 = *(const float4*)&ap[ks * 32 + l4 * 8];
                float4 x1 = *(const float4*)&ap[ks * 32 + l4 * 8 + 4];
                bf16x8 a = {f2bf(x0.x), f2bf(x0.y), f2bf(x0.z), f2bf(x0.w),
                            f2bf(x1.x), f2bf(x1.y), f2bf(x1.z), f2bf(x1.w)};
                acc0 = __builtin_amdgcn_mfma_f32_16x16x32_bf16(a, bw[0][ks], acc0, 0, 0, 0);
                acc1 = __builtin_amdgcn_mfma_f32_16x16x32_bf16(a, bw[1][ks], acc1, 0, 0, 0);
            }
#pragma unroll
            for (int r = 0; r < 4; r++) {
                int er = m * 16 + l4 * 4 + r;
                t1_s[er * 136 + n0 + l15] = f2bf(ssp(acc0[r]));
                t1_s[er * 136 + n0 + 16 + l15] = f2bf(ssp(acc1[r]));
            }
        }
    }
    __syncthreads();

    // GEMM2: v_new = v + (t1 @ u2 + ub2); write vb, t2_s(bf16)
    {
        bf16x8 bw[2][4];
        float bias[2];
#pragma unroll
        for (int n = 0; n < 2; n++) {
            bias[n] = ub2[n0 + n * 16 + l15];
#pragma unroll
            for (int ks = 0; ks < 4; ks++)
                bw[n][ks] = *(const bf16x8*)&u2t[(n0 + n * 16 + l15) * 128 + ks * 32 + l4 * 8];
        }
#pragma unroll
        for (int m = 0; m < 4; m++) {
            f32x4 acc0 = {bias[0], bias[0], bias[0], bias[0]};
            f32x4 acc1 = {bias[1], bias[1], bias[1], bias[1]};
#pragma unroll
            for (int ks = 0; ks < 4; ks++) {
                bf16x8 a = *(const bf16x8*)&t1_s[(m * 16 + l15) * 136 + ks * 32 + l4 * 8];
                acc0 = __builtin_amdgcn_mfma_f32_16x16x32_bf16(a, bw[0][ks], acc0, 0, 0, 0);
                acc1 = __builtin_amdgcn_mfma_f32_16x16x32_bf16(a, bw[1][ks], acc1, 0, 0, 0);
            }
#pragma unroll
            for (int r = 0; r < 4; r++) {
                int er = m * 16 + l4 * 4 + r;
                int gn = nb0 + er;
                if (gn < N_) {
                    size_t i0 = (size_t)gn * HH + n0 + l15;
                    size_t i1 = (size_t)gn * HH + n0 + 16 + l15;
                    float v0 = vb[i0] + acc0[r];
                    float v1 = vb[i1] + acc1[r];
                    vb[i0] = v0;
                    vb[i1] = v1;
                    t2_s[er * 136 + n0 + l15] = f2bf(v0);
                    t2_s[er * 136 + n0 + 16 + l15] = f2bf(v1);
                } else {
                    t2_s[er * 136 + n0 + l15] = 0;
                    t2_s[er * 136 + n0 + 16 + l15] = 0;
                }
            }
        }
    }
    __syncthreads();

    // GEMM3: vproj_next = v_new @ lin_w[l+1]
    if (lwt_next) {
        bf16x8 bw[2][4];
#pragma unroll
        for (int n = 0; n < 2; n++)
#pragma unroll
            for (int ks = 0; ks < 4; ks++)
                bw[n][ks] = *(const bf16x8*)&lwt_next[(n0 + n * 16 + l15) * 128 + ks * 32 + l4 * 8];
#pragma unroll
        for (int m = 0; m < 4; m++) {
            f32x4 acc0 = {0.f, 0.f, 0.f, 0.f}, acc1 = {0.f, 0.f, 0.f, 0.f};
#pragma unroll
            for (int ks = 0; ks < 4; ks++) {
                bf16x8 a = *(const bf16x8*)&t2_s[(m * 16 + l15) * 136 + ks * 32 + l4 * 8];
                acc0 = __builtin_amdgcn_mfma_f32_16x16x32_bf16(a, bw[0][ks], acc0, 0, 0, 0);
                acc1 = __builtin_amdgcn_mfma_f32_16x16x32_bf16(a, bw[1][ks], acc1, 0, 0, 0);
            }
#pragma unroll
            for (int r = 0; r < 4; r++) {
                int gn = nb0 + m * 16 + l4 * 4 + r;
                if (gn < N_) {
                    vproj[(size_t)gn * FF + n0 + l15] = acc0[r];
                    vproj[(size_t)gn * FF + n0 + 16 + l15] = acc1[r];
                }
            }
        }
    }
}

extern "C" void kernel_launch(void* const* d_in, const int* in_sizes, int n_in,
                              void* d_out, int out_size, void* d_ws, size_t ws_size,
                              hipStream_t stream) {
    const float* v = (const float*)d_in[0];
    const float* pos = (const float*)d_in[1];
    const float* offs = (const float*)d_in[2];
    const int* edges = (const int*)d_in[3];
    const float* lin_w = (const float*)d_in[4];
    const float* w1 = (const float*)d_in[5];
    const float* b1 = (const float*)d_in[6];
    const float* w2 = (const float*)d_in[7];
    const float* b2 = (const float*)d_in[8];
    const float* u1 = (const float*)d_in[9];
    const float* ub1 = (const float*)d_in[10];
    const float* u2 = (const float*)d_in[11];
    const float* ub2 = (const float*)d_in[12];

    const int N = in_sizes[0] / HH;
    const int E = in_sizes[3] / 2;
    const int* row = edges;
    const int* col = edges + E;

    char* base = (char*)d_ws;
    int* counts = (int*)base;   base += (size_t)N * 4;
    int* woff = (int*)base;     base += (size_t)N * 4;
    int* srow = (int*)base;     base += (size_t)E * 4;
    int* scol = (int*)base;     base += (size_t)E * 4;
    float* sdist = (float*)base; base += (size_t)E * 4;
    float* sCb = (float*)base;  base += (size_t)E * 4;
    float* vproj = (float*)base; base += (size_t)N * FF * 4;
    float* agg = (float*)base;  base += (size_t)N * FF * 4;
    float* vbuf = (float*)base; base += (size_t)N * HH * 4;
    short* w1t = (short*)base;  base += (size_t)NLAYERS * FF * 64 * 2;
    short* w2t = (short*)base;  base += (size_t)NLAYERS * FF * FF * 2;
    short* u1t = (short*)base;  base += (size_t)NLAYERS * FF * FF * 2;
    short* u2t = (short*)base;  base += (size_t)NLAYERS * FF * FF * 2;
    short* lin_wt = (short*)base;

    const int EB = (E + 255) / 256;
    const int NB = (N + 63) / 64;

    hipMemsetAsync(counts, 0, (size_t)N * 4, stream);
    hist_kernel<<<EB, 256, 0, stream>>>(col, counts, E);
    scan_kernel<<<1, 1024, 0, stream>>>(counts, woff, N);
    scatter_kernel<<<EB, 256, 0, stream>>>(pos, offs, row, col, woff, srow, scol,
                                           sdist, sCb, E);
    prep_kernel<<<(NLAYERS * FF * FF + 255) / 256, 256, 0, stream>>>(
        w1, w2, u1, u2, lin_w, w1t, w2t, u1t, u2t, lin_wt);
    hipMemcpyAsync(vbuf, v, (size_t)N * HH * sizeof(float),
                   hipMemcpyDeviceToDevice, stream);
    vproj0_kernel<<<NB, 256, 0, stream>>>(v, lin_wt, vproj, N);

    for (int l = 0; l < NLAYERS; l++) {
        hipMemsetAsync(agg, 0, (size_t)N * FF * sizeof(float), stream);
        edge_mfma_kernel<<<(E + 63) / 64, 256, 0, stream>>>(
            sdist, sCb, vproj, srow, scol, w1t + (size_t)l * FF * 64,
            b1 + (size_t)l * FF, w2t + (size_t)l * FF * FF, b2 + (size_t)l * FF,
            agg, E);
        node_mfma_kernel<<<NB, 256, 0, stream>>>(
            agg, u1t + (size_t)l * FF * FF, ub1 + (size_t)l * HH,
            u2t + (size_t)l * FF * FF, ub2 + (size_t)l * HH, vbuf,
            (l + 1 < NLAYERS) ? (lin_wt + (size_t)(l + 1) * FF * FF) : nullptr,
            vproj, N);
    }
    hipMemcpyAsync(d_out, vbuf, (size_t)N * HH * sizeof(float),
                   hipMemcpyDeviceToDevice, stream);
}

// Round 4
// 880.953 us; speedup vs baseline: 4.2611x; 1.4619x over previous
//
#include <hip/hip_runtime.h>
#include <hip/hip_bf16.h>
#include <math.h>

#define HH 128
#define FF 128
#define GG 50
#define NLAYERS 6

typedef __attribute__((ext_vector_type(8))) short bf16x8;
typedef __attribute__((ext_vector_type(4))) float f32x4;

static __device__ __forceinline__ float ssp(float x) {
    return fmaxf(x, 0.f) + __logf(1.f + __expf(-fabsf(x))) - 0.6931471805599453f;
}

static __device__ __forceinline__ short f2bf(float x) {
    union { float f; unsigned u; } c; c.f = x;
    unsigned r = (c.u + 0x7FFF + ((c.u >> 16) & 1)) >> 16;
    return (short)r;
}

static __device__ __forceinline__ float bf2f(short x) {
    union { unsigned u; float f; } c;
    c.u = ((unsigned)(unsigned short)x) << 16;
    return c.f;
}

// ---------------- sort pipeline: hist -> scan -> scatter ----------------
__global__ void hist_kernel(const int* __restrict__ col, int* __restrict__ counts, int E_) {
    int e = blockIdx.x * 256 + threadIdx.x;
    if (e < E_) atomicAdd(&counts[col[e]], 1);
}

__global__ __launch_bounds__(1024) void scan_kernel(const int* __restrict__ counts,
                                                    int* __restrict__ offsets, int N_) {
    __shared__ int wsum[16];
    __shared__ int carry_s;
    const int tid = threadIdx.x;
    const int lane = tid & 63, wid = tid >> 6;
    if (tid == 0) carry_s = 0;
    __syncthreads();
    for (int base = 0; base < N_; base += 1024) {
        int i = base + tid;
        int val = (i < N_) ? counts[i] : 0;
        int x = val;
#pragma unroll
        for (int d = 1; d < 64; d <<= 1) {
            int t = __shfl_up(x, d, 64);
            if (lane >= d) x += t;
        }
        if (lane == 63) wsum[wid] = x;
        int carry = carry_s;
        __syncthreads();
        if (wid == 0) {
            int s = (lane < 16) ? wsum[lane] : 0;
#pragma unroll
            for (int d = 1; d < 16; d <<= 1) {
                int t = __shfl_up(s, d, 64);
                if (lane >= d) s += t;
            }
            if (lane < 16) wsum[lane] = s;
            if (lane == 15) carry_s = carry + s;
        }
        __syncthreads();
        int woffset = (wid > 0) ? wsum[wid - 1] : 0;
        if (i < N_) offsets[i] = carry + woffset + x - val;  // exclusive
        __syncthreads();
    }
}

__global__ void scatter_kernel(const float* __restrict__ pos,
                               const float* __restrict__ offs,
                               const int* __restrict__ row,
                               const int* __restrict__ col,
                               int* __restrict__ woff,
                               int* __restrict__ srow, int* __restrict__ scol,
                               float* __restrict__ sdist, float* __restrict__ sCb,
                               int E_) {
    int e = blockIdx.x * 256 + threadIdx.x;
    if (e >= E_) return;
    int r = row[e], c = col[e];
    float dx = pos[c * 3 + 0] + offs[e * 3 + 0] - pos[r * 3 + 0];
    float dy = pos[c * 3 + 1] + offs[e * 3 + 1] - pos[r * 3 + 1];
    float dz = pos[c * 3 + 2] + offs[e * 3 + 2] - pos[r * 3 + 2];
    float d = sqrtf(dx * dx + dy * dy + dz * dz);
    int p = atomicAdd(&woff[c], 1);
    srow[p] = r;
    scol[p] = c;
    sdist[p] = d;
    sCb[p] = 0.5f * (cosf(d * 0.6283185307179586f) + 1.0f);
}

// ------------- prep: transpose + bf16 all weights (all layers) -------------
__global__ __launch_bounds__(256) void prep_kernel(
    const float* __restrict__ w1, const float* __restrict__ w2,
    const float* __restrict__ u1, const float* __restrict__ u2,
    const float* __restrict__ lin_w,
    short* __restrict__ w1t, short* __restrict__ w2t,
    short* __restrict__ u1t, short* __restrict__ u2t, short* __restrict__ lin_wt) {
    int idx = blockIdx.x * 256 + threadIdx.x;
    if (idx < NLAYERS * FF * FF) {
        int l = idx >> 14, r = idx & 16383, a = r >> 7, b = r & 127;
        size_t src = (size_t)l * FF * FF + (size_t)b * FF + a;  // [l][b][a]
        w2t[idx] = f2bf(w2[src]);
        u1t[idx] = f2bf(u1[src]);
        u2t[idx] = f2bf(u2[src]);
        lin_wt[idx] = f2bf(lin_w[src]);
    }
    if (idx < NLAYERS * FF * 64) {
        int l = idx >> 13, r = idx & 8191, fo = r >> 6, g = r & 63;
        w1t[idx] = f2bf(g < GG ? w1[((size_t)l * GG + g) * FF + fo] : 0.f);
    }
}

// ---------------- vproj0 = v(f32) @ lin_w[0]  via MFMA ----------------
__global__ __launch_bounds__(256) void vproj0_kernel(const float* __restrict__ vb,
                                                     const short* __restrict__ lwt,
                                                     float* __restrict__ out, int N_) {
    const int tid = threadIdx.x;
    const int lane = tid & 63, wave = tid >> 6;
    const int l15 = lane & 15, l4 = lane >> 4;
    const int n0 = wave * 32;
    const int nb0 = blockIdx.x * 64;
    bf16x8 bw[2][4];
#pragma unroll
    for (int n = 0; n < 2; n++)
#pragma unroll
        for (int ks = 0; ks < 4; ks++)
            bw[n][ks] = *(const bf16x8*)&lwt[(n0 + n * 16 + l15) * 128 + ks * 32 + l4 * 8];
#pragma unroll
    for (int m = 0; m < 4; m++) {
        f32x4 acc0 = {0.f, 0.f, 0.f, 0.f}, acc1 = {0.f, 0.f, 0.f, 0.f};
        int arow = nb0 + m * 16 + l15;
        const float* ap = &vb[(size_t)(arow < N_ ? arow : 0) * HH];
#pragma unroll
        for (int ks = 0; ks < 4; ks++) {
            float4 x0 = *(const float4*)&ap[ks * 32 + l4 * 8];
            float4 x1 = *(const float4*)&ap[ks * 32 + l4 * 8 + 4];
            bf16x8 a = {f2bf(x0.x), f2bf(x0.y), f2bf(x0.z), f2bf(x0.w),
                        f2bf(x1.x), f2bf(x1.y), f2bf(x1.z), f2bf(x1.w)};
            acc0 = __builtin_amdgcn_mfma_f32_16x16x32_bf16(a, bw[0][ks], acc0, 0, 0, 0);
            acc1 = __builtin_amdgcn_mfma_f32_16x16x32_bf16(a, bw[1][ks], acc1, 0, 0, 0);
        }
#pragma unroll
        for (int r = 0; r < 4; r++) {
            int gn = nb0 + m * 16 + l4 * 4 + r;
            if (gn < N_) {
                out[(size_t)gn * FF + n0 + l15] = acc0[r];
                out[(size_t)gn * FF + n0 + 16 + l15] = acc1[r];
            }
        }
    }
}

// ---------------- fused edge kernel (MFMA + sorted-run scatter) ----------------
// LDS pool (shorts): [demb 64x72 | h1 64x136] aliased by [wf(bf16) 64x132]
__global__ __launch_bounds__(256, 6) void edge_mfma_kernel(
    const float* __restrict__ sdist, const float* __restrict__ sCb,
    const float* __restrict__ vproj, const int* __restrict__ srow,
    const int* __restrict__ scol, const short* __restrict__ w1t,
    const float* __restrict__ b1, const short* __restrict__ w2t,
    const float* __restrict__ b2, float* __restrict__ agg, int E_) {
    __shared__ __align__(16) short lds_pool[64 * 72 + 64 * 136];
    __shared__ int srow_s[64], scol_s[64];
    short* demb_s = lds_pool;             // [64][72]
    short* h1_s = lds_pool + 64 * 72;     // [64][136]
    short* wf_s = lds_pool;               // [64][132] bf16, alias (used after h1)
    const int tid = threadIdx.x;
    const int lane = tid & 63, wave = tid >> 6;
    const int l15 = lane & 15, l4 = lane >> 4;
    const int n0 = wave * 32;
    const int e0 = blockIdx.x * 64;

    bf16x8 bw1[2][2], bw2[2][4];
    float bias1[2], bias2[2];
#pragma unroll
    for (int n = 0; n < 2; n++) {
        const int fo = n0 + n * 16 + l15;
        bias1[n] = b1[fo];
        bias2[n] = b2[fo];
#pragma unroll
        for (int ks = 0; ks < 2; ks++)
            bw1[n][ks] = *(const bf16x8*)&w1t[fo * 64 + ks * 32 + l4 * 8];
#pragma unroll
        for (int ks = 0; ks < 4; ks++)
            bw2[n][ks] = *(const bf16x8*)&w2t[fo * 128 + ks * 32 + l4 * 8];
    }

    // stage sorted indices (clamped; OOB edges have wf=0 and col=last valid)
    if (tid < 64) {
        int ge = e0 + tid;
        if (ge >= E_) ge = E_ - 1;
        srow_s[tid] = srow[ge];
        scol_s[tid] = scol[ge];
    }

    const float STEP = 5.0f / 49.0f;
    const float COEFF = -0.5f / (STEP * STEP);
    for (int idx = tid; idx < 64 * 64; idx += 256) {
        int e = idx >> 6, g = idx & 63;
        int ge = e0 + e;
        float d = sdist[ge < E_ ? ge : 0];
        float x = fmaf((float)g, -STEP, d);
        demb_s[e * 72 + g] = f2bf((g < GG) ? __expf(COEFF * x * x) : 0.f);
    }
    __syncthreads();

    // GEMM1: h1 = ssp(demb @ w1 + b1)
#pragma unroll
    for (int m = 0; m < 4; m++) {
        bf16x8 a0 = *(const bf16x8*)&demb_s[(m * 16 + l15) * 72 + l4 * 8];
        bf16x8 a1 = *(const bf16x8*)&demb_s[(m * 16 + l15) * 72 + 32 + l4 * 8];
#pragma unroll
        for (int n = 0; n < 2; n++) {
            f32x4 acc = {bias1[n], bias1[n], bias1[n], bias1[n]};
            acc = __builtin_amdgcn_mfma_f32_16x16x32_bf16(a0, bw1[n][0], acc, 0, 0, 0);
            acc = __builtin_amdgcn_mfma_f32_16x16x32_bf16(a1, bw1[n][1], acc, 0, 0, 0);
            const int f = n0 + n * 16 + l15;
#pragma unroll
            for (int r = 0; r < 4; r++)
                h1_s[(m * 16 + l4 * 4 + r) * 136 + f] = f2bf(ssp(acc[r]));
        }
    }
    __syncthreads();

    // GEMM2 into registers
    f32x4 accA[4], accB[4];
#pragma unroll
    for (int m = 0; m < 4; m++) {
        accA[m] = {bias2[0], bias2[0], bias2[0], bias2[0]};
        accB[m] = {bias2[1], bias2[1], bias2[1], bias2[1]};
#pragma unroll
        for (int ks = 0; ks < 4; ks++) {
            bf16x8 a = *(const bf16x8*)&h1_s[(m * 16 + l15) * 136 + ks * 32 + l4 * 8];
            accA[m] = __builtin_amdgcn_mfma_f32_16x16x32_bf16(a, bw2[0][ks], accA[m], 0, 0, 0);
            accB[m] = __builtin_amdgcn_mfma_f32_16x16x32_bf16(a, bw2[1][ks], accB[m], 0, 0, 0);
        }
    }
    __syncthreads();  // all h1 reads done; wf_s may alias

    // store Wf * C to LDS (bf16)
#pragma unroll
    for (int m = 0; m < 4; m++) {
#pragma unroll
        for (int r = 0; r < 4; r++) {
            int er = m * 16 + l4 * 4 + r;
            int ge = e0 + er;
            float cb = (ge < E_) ? sCb[ge] : 0.f;
            wf_s[er * 132 + n0 + l15] = f2bf(accA[m][r] * cb);
            wf_s[er * 132 + n0 + 16 + l15] = f2bf(accB[m][r] * cb);
        }
    }
    __syncthreads();

    // serial walk: 4 subs x 16 edges, 2 features/thread, run-accumulate
    {
        const int sub = tid >> 6;        // 0..3
        const int fl = tid & 63;         // features fl, fl+64
        const int base = sub * 16;
        float acc0 = 0.f, acc1 = 0.f;
        int cur = scol_s[base];
#pragma unroll 4
        for (int i = 0; i < 16; i++) {
            int e = base + i;
            int r_ = srow_s[e], c_ = scol_s[e];
            const float* vp = &vproj[(size_t)r_ * FF];
            float w0 = bf2f(wf_s[e * 132 + fl]);
            float w1v = bf2f(wf_s[e * 132 + 64 + fl]);
            float v0 = vp[fl], v1 = vp[64 + fl];
            if (c_ != cur) {
                unsafeAtomicAdd(&agg[(size_t)cur * FF + fl], acc0);
                unsafeAtomicAdd(&agg[(size_t)cur * FF + 64 + fl], acc1);
                acc0 = 0.f; acc1 = 0.f; cur = c_;
            }
            acc0 = fmaf(w0, v0, acc0);
            acc1 = fmaf(w1v, v1, acc1);
        }
        unsafeAtomicAdd(&agg[(size_t)cur * FF + fl], acc0);
        unsafeAtomicAdd(&agg[(size_t)cur * FF + 64 + fl], acc1);
    }
}

// ------- fused node kernel (32 rows/block): v += ssp(agg@u1+b)@u2+b ; vproj_next
__global__ __launch_bounds__(256) void node_mfma_kernel(
    const float* __restrict__ agg, const short* __restrict__ u1t,
    const float* __restrict__ ub1, const short* __restrict__ u2t,
    const float* __restrict__ ub2, float* __restrict__ vb,
    const short* __restrict__ lwt_next, float* __restrict__ vproj, int N_) {
    __shared__ __align__(16) short t1_s[32 * 136];
    __shared__ __align__(16) short t2_s[32 * 136];
    const int tid = threadIdx.x;
    const int lane = tid & 63, wave = tid >> 6;
    const int l15 = lane & 15, l4 = lane >> 4;
    const int n0 = wave * 32;
    const int nb0 = blockIdx.x * 32;

    // GEMM1: t1 = ssp(agg @ u1 + ub1)
    {
        bf16x8 bw[2][4];
        float bias[2];
#pragma unroll
        for (int n = 0; n < 2; n++) {
            bias[n] = ub1[n0 + n * 16 + l15];
#pragma unroll
            for (int ks = 0; ks < 4; ks++)
                bw[n][ks] = *(const bf16x8*)&u1t[(n0 + n * 16 + l15) * 128 + ks * 32 + l4 * 8];
        }
#pragma unroll
        for (int m = 0; m < 2; m++) {
            int arow = nb0 + m * 16 + l15;
            const float* ap = &agg[(size_t)(arow < N_ ? arow : 0) * FF];
            f32x4 acc0 = {bias[0], bias[0], bias[0], bias[0]};
            f32x4 acc1 = {bias[1], bias[1], bias[1], bias[1]};
#pragma unroll
            for (int ks = 0; ks < 4; ks++) {
                float4 x0 = *(const float4*)&ap[ks * 32 + l4 * 8];
                float4 x1 = *(const float4*)&ap[ks * 32 + l4 * 8 + 4];
                bf16x8 a = {f2bf(x0.x), f2bf(x0.y), f2bf(x0.z), f2bf(x0.w),
                            f2bf(x1.x), f2bf(x1.y), f2bf(x1.z), f2bf(x1.w)};
                acc0 = __builtin_amdgcn_mfma_f32_16x16x32_bf16(a, bw[0][ks], acc0, 0, 0, 0);
                acc1 = __builtin_amdgcn_mfma_f32_16x16x32_bf16(a, bw[1][ks], acc1, 0, 0, 0);
            }
#pragma unroll
            for (int r = 0; r < 4; r++) {
                int er = m * 16 + l4 * 4 + r;
                t1_s[er * 136 + n0 + l15] = f2bf(ssp(acc0[r]));
                t1_s[er * 136 + n0 + 16 + l15] = f2bf(ssp(acc1[r]));
            }
        }
    }
    __syncthreads();

    // GEMM2: v_new = v + (t1 @ u2 + ub2)
    {
        bf16x8 bw[2][4];
        float bias[2];
#pragma unroll
        for (int n = 0; n < 2; n++) {
            bias[n] = ub2[n0 + n * 16 + l15];
#pragma unroll
            for (int ks = 0; ks < 4; ks++)
                bw[n][ks] = *(const bf16x8*)&u2t[(n0 + n * 16 + l15) * 128 + ks * 32 + l4 * 8];
        }
#pragma unroll
        for (int m = 0; m < 2; m++) {
            f32x4 acc0 = {bias[0], bias[0], bias[0], bias[0]};
            f32x4 acc1 = {bias[1], bias[1], bias[1], bias[1]};
#pragma unroll
            for (int ks = 0; ks < 4; ks++) {
                bf16x8 a = *(const bf16x8*)&t1_s[(m * 16 + l15) * 136 + ks * 32 + l4 * 8];
                acc0 = __builtin_amdgcn_mfma_f32_16x16x32_bf16(a, bw[0][ks], acc0, 0, 0, 0);
                acc1 = __builtin_amdgcn_mfma_f32_16x16x32_bf16(a, bw[1][ks], acc1, 0, 0, 0);
            }
#pragma unroll
            for (int r = 0; r < 4; r++) {
                int er = m * 16 + l4 * 4 + r;
                int gn = nb0 + er;
                if (gn < N_) {
                    size_t i0 = (size_t)gn * HH + n0 + l15;
                    size_t i1 = (size_t)gn * HH + n0 + 16 + l15;
                    float v0 = vb[i0] + acc0[r];
                    float v1 = vb[i1] + acc1[r];
                    vb[i0] = v0;
                    vb[i1] = v1;
                    t2_s[er * 136 + n0 + l15] = f2bf(v0);
                    t2_s[er * 136 + n0 + 16 + l15] = f2bf(v1);
                } else {
                    t2_s[er * 136 + n0 + l15] = 0;
                    t2_s[er * 136 + n0 + 16 + l15] = 0;
                }
            }
        }
    }
    __syncthreads();

    // GEMM3: vproj_next = v_new @ lin_w[l+1]
    if (lwt_next) {
        bf16x8 bw[2][4];
#pragma unroll
        for (int n = 0; n < 2; n++)
#pragma unroll
            for (int ks = 0; ks < 4; ks++)
                bw[n][ks] = *(const bf16x8*)&lwt_next[(n0 + n * 16 + l15) * 128 + ks * 32 + l4 * 8];
#pragma unroll
        for (int m = 0; m < 2; m++) {
            f32x4 acc0 = {0.f, 0.f, 0.f, 0.f}, acc1 = {0.f, 0.f, 0.f, 0.f};
#pragma unroll
            for (int ks = 0; ks < 4; ks++) {
                bf16x8 a = *(const bf16x8*)&t2_s[(m * 16 + l15) * 136 + ks * 32 + l4 * 8];
                acc0 = __builtin_amdgcn_mfma_f32_16x16x32_bf16(a, bw[0][ks], acc0, 0, 0, 0);
                acc1 = __builtin_amdgcn_mfma_f32_16x16x32_bf16(a, bw[1][ks], acc1, 0, 0, 0);
            }
#pragma unroll
            for (int r = 0; r < 4; r++) {
                int gn = nb0 + m * 16 + l4 * 4 + r;
                if (gn < N_) {
                    vproj[(size_t)gn * FF + n0 + l15] = acc0[r];
                    vproj[(size_t)gn * FF + n0 + 16 + l15] = acc1[r];
                }
            }
        }
    }
}

extern "C" void kernel_launch(void* const* d_in, const int* in_sizes, int n_in,
                              void* d_out, int out_size, void* d_ws, size_t ws_size,
                              hipStream_t stream) {
    const float* v = (const float*)d_in[0];
    const float* pos = (const float*)d_in[1];
    const float* offs = (const float*)d_in[2];
    const int* edges = (const int*)d_in[3];
    const float* lin_w = (const float*)d_in[4];
    const float* w1 = (const float*)d_in[5];
    const float* b1 = (const float*)d_in[6];
    const float* w2 = (const float*)d_in[7];
    const float* b2 = (const float*)d_in[8];
    const float* u1 = (const float*)d_in[9];
    const float* ub1 = (const float*)d_in[10];
    const float* u2 = (const float*)d_in[11];
    const float* ub2 = (const float*)d_in[12];

    const int N = in_sizes[0] / HH;
    const int E = in_sizes[3] / 2;
    const int* row = edges;
    const int* col = edges + E;

    char* base = (char*)d_ws;
    int* counts = (int*)base;   base += (size_t)N * 4;
    int* woff = (int*)base;     base += (size_t)N * 4;
    int* srow = (int*)base;     base += (size_t)E * 4;
    int* scol = (int*)base;     base += (size_t)E * 4;
    float* sdist = (float*)base; base += (size_t)E * 4;
    float* sCb = (float*)base;  base += (size_t)E * 4;
    float* vproj = (float*)base; base += (size_t)N * FF * 4;
    float* agg = (float*)base;  base += (size_t)N * FF * 4;
    float* vbuf = (float*)base; base += (size_t)N * HH * 4;
    short* w1t = (short*)base;  base += (size_t)NLAYERS * FF * 64 * 2;
    short* w2t = (short*)base;  base += (size_t)NLAYERS * FF * FF * 2;
    short* u1t = (short*)base;  base += (size_t)NLAYERS * FF * FF * 2;
    short* u2t = (short*)base;  base += (size_t)NLAYERS * FF * FF * 2;
    short* lin_wt = (short*)base;

    const int EB = (E + 255) / 256;
    const int NB64 = (N + 63) / 64;
    const int NB32 = (N + 31) / 32;

    hipMemsetAsync(counts, 0, (size_t)N * 4, stream);
    hist_kernel<<<EB, 256, 0, stream>>>(col, counts, E);
    scan_kernel<<<1, 1024, 0, stream>>>(counts, woff, N);
    scatter_kernel<<<EB, 256, 0, stream>>>(pos, offs, row, col, woff, srow, scol,
                                           sdist, sCb, E);
    prep_kernel<<<(NLAYERS * FF * FF + 255) / 256, 256, 0, stream>>>(
        w1, w2, u1, u2, lin_w, w1t, w2t, u1t, u2t, lin_wt);
    hipMemcpyAsync(vbuf, v, (size_t)N * HH * sizeof(float),
                   hipMemcpyDeviceToDevice, stream);
    vproj0_kernel<<<NB64, 256, 0, stream>>>(v, lin_wt, vproj, N);

    for (int l = 0; l < NLAYERS; l++) {
        hipMemsetAsync(agg, 0, (size_t)N * FF * sizeof(float), stream);
        edge_mfma_kernel<<<(E + 63) / 64, 256, 0, stream>>>(
            sdist, sCb, vproj, srow, scol, w1t + (size_t)l * FF * 64,
            b1 + (size_t)l * FF, w2t + (size_t)l * FF * FF, b2 + (size_t)l * FF,
            agg, E);
        node_mfma_kernel<<<NB32, 256, 0, stream>>>(
            agg, u1t + (size_t)l * FF * FF, ub1 + (size_t)l * HH,
            u2t + (size_t)l * FF * FF, ub2 + (size_t)l * HH, vbuf,
            (l + 1 < NLAYERS) ? (lin_wt + (size_t)(l + 1) * FF * FF) : nullptr,
            vproj, N);
    }
    hipMemcpyAsync(d_out, vbuf, (size_t)N * HH * sizeof(float),
                   hipMemcpyDeviceToDevice, stream);
}